// Round 3
// baseline (9.769 us; speedup 1.0000x reference)
//

#include <hip/hip_runtime.h>
#include <math.h>

// Problem constants from setup_inputs(): pred [N,T,C] f32, target [N,S] i32.
#define N_SAMPLES 128
#define T_DIM 256
#define C_DIM 2048
#define S_DIM 64
#define LOSS_WEIGHT 1.0f

// total = sum_i( valid_i ? -pred[i,0,target[i,0]] * W : 0 ) / N
// valid_i = all(target[i,:] != -1) && !isnan(loss_i); base term is exactly 0.
//
// Latency-bound single dispatch. 128 threads (2 waves), one per sample:
//  - first int4 of the target row is loaded immediately; the dependent pred
//    gather issues as soon as it lands (critical path = 2 memory latencies,
//    L3-warm during timed replays)
//  - remaining 15 int4 validity loads are independent and pipeline under it
//  - all validity logic in registers; single barrier to combine 2 waves
__global__ void __launch_bounds__(128)
mapping_ctc_loss_kernel(const float* __restrict__ pred,
                        const int* __restrict__ target,
                        float* __restrict__ out) {
    const int tid = threadIdx.x;  // one thread per sample; blockDim.x == 128

    // Per-sample row: 64 ints = 16 int4, 256 B contiguous.
    const int4* tv = (const int4*)(target + (size_t)tid * S_DIM);

    // Head of the critical path: first vector (contains t0).
    const int4 v0 = tv[0];
    const float loss = -pred[(size_t)tid * (T_DIM * C_DIM) + (size_t)v0.x];

    // Validity scan, fully in registers (independent loads, pipelined).
    bool invalid = (v0.x == -1) | (v0.y == -1) | (v0.z == -1) | (v0.w == -1);
    #pragma unroll
    for (int k = 1; k < 16; ++k) {
        const int4 v = tv[k];
        invalid |= (v.x == -1) | (v.y == -1) | (v.z == -1) | (v.w == -1);
    }

    float contrib = (!invalid && !isnan(loss)) ? loss * LOSS_WEIGHT : 0.0f;

    // Wave-level reduction (64 lanes), then combine the two waves.
    #pragma unroll
    for (int off = 32; off > 0; off >>= 1) {
        contrib += __shfl_down(contrib, off, 64);
    }

    __shared__ float s_wsum[2];
    if ((tid & 63) == 0) s_wsum[tid >> 6] = contrib;
    __syncthreads();
    if (tid == 0) {
        out[0] = (s_wsum[0] + s_wsum[1]) * (1.0f / (float)N_SAMPLES);
    }
}

extern "C" void kernel_launch(void* const* d_in, const int* in_sizes, int n_in,
                              void* d_out, int out_size, void* d_ws, size_t ws_size,
                              hipStream_t stream) {
    const float* pred  = (const float*)d_in[0];  // [N, T, C] f32
    const int* target  = (const int*)d_in[1];    // [N, S] i32
    float* out = (float*)d_out;                  // scalar f32

    mapping_ctc_loss_kernel<<<1, 128, 0, stream>>>(pred, target, out);
}